// Round 5
// baseline (508.387 us; speedup 1.0000x reference)
//
#include <hip/hip_runtime.h>
#include <hip/hip_bf16.h>

typedef float f32x4 __attribute__((ext_vector_type(4)));
typedef short s16x8 __attribute__((ext_vector_type(8)));
typedef short s16x4 __attribute__((ext_vector_type(4)));
typedef __bf16 bf16x8 __attribute__((ext_vector_type(8)));
typedef unsigned short u16;

#define DEVI __device__ __forceinline__

static constexpr int    HW      = 16384;
static constexpr size_t BSTRIDE = (size_t)256 * HW;

// ---- workspace byte offsets ----
static constexpr size_t oXBT   = 0;                                    // bf16 [8][HW][256]
static constexpr size_t oEK    = oXBT  + (size_t)8 * HW * 256 * 2;     // bf16 [8][256][HW] exp(keys)
static constexpr size_t oQT    = oEK   + (size_t)8 * 256 * HW * 2;     // bf16 [8][HW][256] softmaxed Q, transposed
static constexpr size_t oVB    = oQT   + (size_t)8 * HW * 256 * 2;     // bf16 [8][256][HW]
static constexpr size_t oWK    = oVB   + (size_t)8 * 256 * HW * 2;     // bf16 [768][256]
static constexpr size_t oBIAS  = oWK   + (size_t)768 * 256 * 2;        // f32 [768]
static constexpr size_t oISE   = oBIAS + 4096;                         // f32 [8][256] inv row-sum-exp
static constexpr size_t oPS    = oISE  + 8192;                         // f32 [256][8][256] rowsum partials
static constexpr size_t oCTX   = oPS   + (size_t)256 * 2048 * 4;       // f32 [64][32][32]
static constexpr size_t oMB    = oCTX  + (size_t)64 * 1024 * 4;        // bf16 [8][256][256]
static constexpr size_t oCPART = oMB   + (size_t)8 * 256 * 256 * 2;    // f32 [4096][1024]
static constexpr size_t oMPART = oCPART + (size_t)4096 * 1024 * 4;     // f32 [8][8][HW]

DEVI float bf2f(short x) {
  unsigned u = ((unsigned)(unsigned short)x) << 16;
  return __builtin_bit_cast(float, u);
}
DEVI u16 f2bf(float x) { return __builtin_bit_cast(u16, (__bf16)x); }

DEVI void gld16(const void* g, void* l) {
  __builtin_amdgcn_global_load_lds(
      (__attribute__((address_space(1))) void*)(g),
      (__attribute__((address_space(3))) void*)(l), 16, 0, 0);
}

DEVI void cfence() { asm volatile("" ::: "memory"); }

// ---------------- prep: pack Wk|Wq|Wv -> bf16 [768][256], biases -> f32 [768] ----------------
__global__ __launch_bounds__(256) void k_prep(
    const float* __restrict__ Wk, const float* __restrict__ Wq, const float* __restrict__ Wv,
    const float* __restrict__ bk, const float* __restrict__ bq, const float* __restrict__ bv,
    u16* __restrict__ Wkqv, float* __restrict__ bias)
{
  int i = blockIdx.x * 256 + threadIdx.x;
  for (int p = i; p < 768 * 256; p += 64 * 256) {
    float v = (p < 65536) ? Wk[p] : (p < 131072 ? Wq[p - 65536] : Wv[p - 131072]);
    Wkqv[p] = f2bf(v);
  }
  if (i < 768) bias[i] = (i < 256) ? bk[i] : (i < 512 ? bq[i - 256] : bv[i - 512]);
}

// ---------------- transpose x [8][256][HW] f32 -> bf16 [8][HW][256], coalesced reads ----------------
__global__ __launch_bounds__(256) void k_transpose(const float* __restrict__ x, u16* __restrict__ out)
{
  __shared__ u16 T[64 * 264];
  const int t = threadIdx.x;
  const int n = blockIdx.y;
  const int s0 = blockIdx.x * 64;
  const int cg = t >> 4;           // 0..15
  const int sl = (t & 15) * 4;     // s offset 0..60
  #pragma unroll
  for (int i = 0; i < 16; ++i) {
    const int c = i * 16 + cg;
    f32x4 v = *(const f32x4*)(x + ((size_t)n * 256 + c) * HW + s0 + sl);
    #pragma unroll
    for (int j = 0; j < 4; ++j) T[(sl + j) * 264 + c] = f2bf(v[j]);
  }
  __syncthreads();
  const int sr = t >> 2, ch = (t & 3) * 64;
  u16* dst = out + (size_t)n * BSTRIDE + (size_t)(s0 + sr) * 256 + ch;
  const u16* srcl = &T[sr * 264 + ch];
  #pragma unroll
  for (int i = 0; i < 8; ++i) *(s16x8*)(dst + i * 8) = *(const s16x8*)(srcl + i * 8);
}

// ---------------- multi-tile pipelined MFMA GEMM: 128x128 tile, BK=32, 4 s-tiles per block --------
// Counted-vmcnt double-buffer rolling across tile boundaries; T2 chunk swizzle both-sides.
// MODE 0: proj (mb 0,1 keys->exp+rowsum; 2,3 softmax-Q -> qT transposed; 4,5 values)
// MODE 1: attn = Mb * qT^T + br, f32 out
template<int MODE>
__global__ __launch_bounds__(256, 4) void k_gemm2(
    const u16* __restrict__ A, const u16* __restrict__ B, const float* __restrict__ bias,
    u16* __restrict__ o_ek, u16* __restrict__ o_qT, u16* __restrict__ o_vb,
    float* __restrict__ o_ps, float* __restrict__ o_f32)
{
  __shared__ u16 smem[16384];        // 32 KiB: A dbuf [2][128][32] | B dbuf [2][128][32]
  const int t = threadIdx.x;
  const int L = blockIdx.x;
  const int n = L & 7;               // batch == XCD
  const int idx = L >> 3;
  int mb, sq;
  if constexpr (MODE == 0) { mb = idx % 6; sq = idx / 6; }   // mb-adjacent -> B-panel L2 reuse
  else                     { mb = idx & 1; sq = idx >> 1; }
  const int m0 = mb * 128;
  const int lane = t & 63;
  const int l15 = lane & 15, l4 = (lane >> 4) & 3;
  const int wv = t >> 6;
  const int wm = (wv & 1) * 64, wn = (wv >> 1) * 64;
  const u16* Ab = A + ((MODE == 0) ? (size_t)0 : (size_t)n * 65536) + (size_t)m0 * 256;
  const u16* Bb = B + (size_t)n * BSTRIDE;
  const int ar = t >> 2;
  const int acs = (((t & 3) ^ (ar & 3)) * 8);   // pre-swizzled source chunk (involution)

  u16* Al = smem;                    // [2][4096]
  u16* Bl = smem + 8192;

  auto STAGE = [&](int it) {         // k-step (it&7) of s-tile (it>>3) into buf (it&1)
    const int buf = it & 1;
    const int k0 = (it & 7) * 32;
    const size_t srow = (size_t)((sq * 4 + (it >> 3)) * 128);
    gld16(Ab + (size_t)ar * 256 + k0 + acs,          Al + buf * 4096 + t * 8);
    gld16(Ab + (size_t)(ar + 64) * 256 + k0 + acs,   Al + buf * 4096 + 2048 + t * 8);
    gld16(Bb + (srow + ar) * 256 + k0 + acs,         Bl + buf * 4096 + t * 8);
    gld16(Bb + (srow + ar + 64) * 256 + k0 + acs,    Bl + buf * 4096 + 2048 + t * 8);
  };

  f32x4 acc[4][4] = {};
  STAGE(0);

  u16* ekb = (MODE == 0) ? o_ek + (size_t)n * BSTRIDE : nullptr;
  u16* vbb = (MODE == 0) ? o_vb + (size_t)n * BSTRIDE : nullptr;
  u16* qtb = (MODE == 0) ? o_qT + (size_t)n * BSTRIDE : nullptr;
  float* ob = (MODE == 1) ? o_f32 + (size_t)n * BSTRIDE : nullptr;

  #pragma unroll 8
  for (int it = 0; it < 32; ++it) {
    if (it < 31) {
      STAGE(it + 1);
      asm volatile("s_waitcnt vmcnt(4)" ::: "memory");   // stage(it) complete, stage(it+1) in flight
    } else {
      asm volatile("s_waitcnt vmcnt(0)" ::: "memory");
    }
    cfence(); __builtin_amdgcn_s_barrier(); cfence();

    const int buf = it & 1;
    bf16x8 af[4], bff[4];
    #pragma unroll
    for (int g = 0; g < 4; ++g) {
      const int mrow = wm + g * 16 + l15;
      const int srw  = wn + g * 16 + l15;
      af[g]  = *(const bf16x8*)&Al[buf * 4096 + mrow * 32 + ((l4 ^ (l15 & 3)) * 8)];
      bff[g] = *(const bf16x8*)&Bl[buf * 4096 + srw  * 32 + ((l4 ^ (l15 & 3)) * 8)];
    }
    __builtin_amdgcn_s_setprio(1);
    #pragma unroll
    for (int mg = 0; mg < 4; ++mg)
      #pragma unroll
      for (int ng = 0; ng < 4; ++ng)
        acc[mg][ng] = __builtin_amdgcn_mfma_f32_16x16x32_bf16(af[mg], bff[ng], acc[mg][ng], 0, 0, 0);
    __builtin_amdgcn_s_setprio(0);

    asm volatile("s_waitcnt lgkmcnt(0)" ::: "memory");   // all frag reads of buf retired
    cfence(); __builtin_amdgcn_s_barrier(); cfence();    // buf safe to overwrite next iter

    if ((it & 7) == 7) {
      // ---------------- per-tile epilogue ----------------
      const int tile = it >> 3;
      const int s0t = (sq * 4 + tile) * 128;
      if constexpr (MODE == 1) {
        #pragma unroll
        for (int mg = 0; mg < 4; ++mg)
          #pragma unroll
          for (int r = 0; r < 4; ++r) {
            const int m = m0 + wm + mg * 16 + l4 * 4 + r;
            const float bb = bias[m];
            float* op = ob + (size_t)m * HW + s0t + wn + l15;
            #pragma unroll
            for (int ng = 0; ng < 4; ++ng) op[ng * 16] = acc[mg][ng][r] + bb;
          }
      } else if (mb < 2) {
        // exp(keys) + deterministic rowsum partials
        const int stile = sq * 4 + tile;
        #pragma unroll
        for (int mg = 0; mg < 4; ++mg)
          #pragma unroll
          for (int r = 0; r < 4; ++r) {
            const int m = m0 + wm + mg * 16 + l4 * 4 + r;
            const float bb = bias[m];
            float e[4], s_ = 0.f;
            #pragma unroll
            for (int ng = 0; ng < 4; ++ng) { e[ng] = __expf(acc[mg][ng][r] + bb); s_ += e[ng]; }
            s_ += __shfl_xor(s_, 1); s_ += __shfl_xor(s_, 2);
            s_ += __shfl_xor(s_, 4); s_ += __shfl_xor(s_, 8);
            if (l15 == 0)
              o_ps[((size_t)(stile * 2 + (wn >> 6))) * 2048 + n * 256 + m] = s_;
            u16* op = ekb + (size_t)m * HW + s0t + wn + l15;
            #pragma unroll
            for (int ng = 0; ng < 4; ++ng) op[ng * 16] = f2bf(e[ng]);
          }
      } else if (mb < 4) {
        // queries: per-head (32-row) softmax over m, transposed s16x4 store to qT[s][m]
        #pragma unroll
        for (int mg = 0; mg < 4; ++mg)
          #pragma unroll
          for (int r = 0; r < 4; ++r) {
            const float bb = bias[m0 + wm + mg * 16 + l4 * 4 + r];
            #pragma unroll
            for (int ng = 0; ng < 4; ++ng) acc[mg][ng][r] += bb;
          }
        #pragma unroll
        for (int hh = 0; hh < 2; ++hh)
          #pragma unroll
          for (int ng = 0; ng < 4; ++ng) {
            float s = 0.f;
            #pragma unroll
            for (int mg = hh * 2; mg < hh * 2 + 2; ++mg)
              #pragma unroll
              for (int r = 0; r < 4; ++r) { const float e = __expf(acc[mg][ng][r]); acc[mg][ng][r] = e; s += e; }
            s += __shfl_xor(s, 16); s += __shfl_xor(s, 32);
            const float inv = 1.f / s;
            #pragma unroll
            for (int mg = hh * 2; mg < hh * 2 + 2; ++mg)
              #pragma unroll
              for (int r = 0; r < 4; ++r) acc[mg][ng][r] *= inv;
          }
        const int mcb = (m0 - 256) + wm;   // 64B-line-complete within block
        #pragma unroll
        for (int mg = 0; mg < 4; ++mg)
          #pragma unroll
          for (int ng = 0; ng < 4; ++ng) {
            s16x4 pk;
            #pragma unroll
            for (int r = 0; r < 4; ++r) pk[r] = (short)f2bf(acc[mg][ng][r]);
            *(s16x4*)(qtb + (size_t)(s0t + wn + ng * 16 + l15) * 256 + mcb + mg * 16 + l4 * 4) = pk;
          }
      } else {
        // values
        #pragma unroll
        for (int mg = 0; mg < 4; ++mg)
          #pragma unroll
          for (int r = 0; r < 4; ++r) {
            const int m = m0 + wm + mg * 16 + l4 * 4 + r;
            const float bb = bias[m];
            u16* op = vbb + (size_t)(m - 512) * HW + s0t + wn + l15;
            #pragma unroll
            for (int ng = 0; ng < 4; ++ng) op[ng * 16] = f2bf(acc[mg][ng][r] + bb);
          }
      }
      #pragma unroll
      for (int mg = 0; mg < 4; ++mg)
        #pragma unroll
        for (int ng = 0; ng < 4; ++ng) acc[mg][ng] = f32x4{0.f, 0.f, 0.f, 0.f};
    }
  }
}

// ---------------- reduce rowsum partials -> inverse ----------------
__global__ __launch_bounds__(256) void k_inv(const float* __restrict__ ps, float* __restrict__ ise)
{
  const int i = blockIdx.x * 256 + threadIdx.x;   // 2048
  float s = 0.f;
  for (int b = 0; b < 256; ++b) s += ps[(size_t)b * 2048 + i];
  ise[i] = 1.f / s;
}

// ---------------- ctx split-K partials + fused attention-map partials ----------------
__global__ __launch_bounds__(64) void k_ctx_part(
    const u16* __restrict__ ek, const u16* __restrict__ vb, const float* __restrict__ ise,
    float* __restrict__ cpart, float* __restrict__ mpart)
{
  const int blk = blockIdx.x;            // nh*64 + chunk
  const int chunk = blk & 63, nh = blk >> 6;
  const int h = nh & 7, n = nh >> 3;
  const int lane = threadIdx.x;
  const int l15 = lane & 15, l4 = lane >> 4;
  const u16* kb = ek + ((size_t)n * 256 + h * 32) * HW;
  const u16* vv = vb + ((size_t)n * 256 + h * 32) * HW;
  const float iv0 = ise[n * 256 + h * 32 + l15];
  const float iv1 = ise[n * 256 + h * 32 + 16 + l15];
  f32x4 acc[2][2] = {};
  float macc[8][8] = {};
  const int sbase = chunk * 256 + l4 * 8;
  #pragma unroll
  for (int ks = 0; ks < 8; ++ks) {
    const int sb = sbase + ks * 32;
    bf16x8 ef[2], vf[2];
    #pragma unroll
    for (int g = 0; g < 2; ++g) {
      ef[g] = *(const bf16x8*)(kb + (size_t)(g * 16 + l15) * HW + sb);
      vf[g] = *(const bf16x8*)(vv + (size_t)(g * 16 + l15) * HW + sb);
    }
    #pragma unroll
    for (int j = 0; j < 8; ++j)
      macc[ks][j] = fmaf(iv0, (float)ef[0][j], fmaf(iv1, (float)ef[1][j], macc[ks][j]));
    #pragma unroll
    for (int a = 0; a < 2; ++a)
      #pragma unroll
      for (int b = 0; b < 2; ++b)
        acc[a][b] = __builtin_amdgcn_mfma_f32_16x16x32_bf16(ef[a], vf[b], acc[a][b], 0, 0, 0);
  }
  float* op = cpart + (size_t)blk * 1024;
  #pragma unroll
  for (int a = 0; a < 2; ++a)
    #pragma unroll
    for (int b = 0; b < 2; ++b)
      #pragma unroll
      for (int r = 0; r < 4; ++r)
        op[(a * 16 + l4 * 4 + r) * 32 + b * 16 + l15] = acc[a][b][r];
  #pragma unroll
  for (int ks = 0; ks < 8; ++ks)
    #pragma unroll
    for (int j = 0; j < 8; ++j) {
      float v = macc[ks][j];
      v += __shfl_xor(v, 1); v += __shfl_xor(v, 2);
      v += __shfl_xor(v, 4); v += __shfl_xor(v, 8);
      macc[ks][j] = v;
    }
  if (l15 == 0) {
    float* mp = mpart + ((size_t)h * 8 + n) * HW + sbase;
    #pragma unroll
    for (int ks = 0; ks < 8; ++ks) {
      f32x4 a = {macc[ks][0], macc[ks][1], macc[ks][2], macc[ks][3]};
      f32x4 b = {macc[ks][4], macc[ks][5], macc[ks][6], macc[ks][7]};
      *(f32x4*)(mp + ks * 32)     = a;
      *(f32x4*)(mp + ks * 32 + 4) = b;
    }
  }
}

// ---------------- reduce ctx partials, normalize; emit context_last (h==7) ----------------
__global__ __launch_bounds__(256) void k_ctx_reduce(
    const float* __restrict__ cpart, const float* __restrict__ ise,
    float* __restrict__ ctx, float* __restrict__ dctx)
{
  const int nh = blockIdx.x, n = nh >> 3, h = nh & 7, t = threadIdx.x;
  f32x4 a = {};
  for (int c = 0; c < 64; ++c) a += *(const f32x4*)(cpart + ((size_t)nh * 64 + c) * 1024 + t * 4);
  const float inv = ise[n * 256 + h * 32 + (t >> 3)];
  a *= inv;
  *(f32x4*)(ctx + (size_t)nh * 1024 + t * 4) = a;
  if (h == 7) *(f32x4*)(dctx + (size_t)n * 1024 + t * 4) = a;
}

// ---------------- M[n][o][h*32+k] = sum_v Wr[o][h*32+v] * ctx[n][h][k][v] ----------------
__global__ __launch_bounds__(256) void k_mmat(
    const float* __restrict__ ctx, const float* __restrict__ Wr, u16* __restrict__ Mb)
{
  const int nh = blockIdx.x, n = nh >> 3, h = nh & 7, o = threadIdx.x;
  __shared__ float cl[1024];
  #pragma unroll
  for (int i = 0; i < 4; ++i) cl[o + i * 256] = ctx[(size_t)nh * 1024 + o + i * 256];
  __syncthreads();
  float wr[32];
  const float* wp = Wr + (size_t)o * 256 + h * 32;
  #pragma unroll
  for (int v = 0; v < 32; ++v) wr[v] = wp[v];
  u16* mp = Mb + ((size_t)n * 256 + o) * 256 + h * 32;
  #pragma unroll 4
  for (int k = 0; k < 32; ++k) {
    float s = 0.f;
    #pragma unroll
    for (int v = 0; v < 32; ++v) s += wr[v] * cl[k * 32 + v];
    mp[k] = f2bf(s);
  }
}

// ---------------- attention_map: sum 8 head partials, /256 ----------------
__global__ __launch_bounds__(256) void k_map_reduce(const float* __restrict__ mpart, float* __restrict__ dmap)
{
  const int i = blockIdx.x * 256 + threadIdx.x;   // 32768 threads, f32x4 each
  f32x4 a = {};
  #pragma unroll
  for (int h = 0; h < 8; ++h) a += *(const f32x4*)(mpart + (size_t)h * 131072 + (size_t)i * 4);
  a *= (1.0f / 256.0f);
  *(f32x4*)(dmap + (size_t)i * 4) = a;
}

extern "C" void kernel_launch(void* const* d_in, const int* in_sizes, int n_in,
                              void* d_out, int out_size, void* d_ws, size_t ws_size,
                              hipStream_t stream)
{
  (void)in_sizes; (void)n_in; (void)out_size; (void)ws_size;
  const float* x  = (const float*)d_in[0];
  const float* Wk = (const float*)d_in[1];
  const float* bk = (const float*)d_in[2];
  const float* Wq = (const float*)d_in[3];
  const float* bq = (const float*)d_in[4];
  const float* Wv = (const float*)d_in[5];
  const float* bv = (const float*)d_in[6];
  const float* Wr = (const float*)d_in[7];
  const float* br = (const float*)d_in[8];

  char* ws = (char*)d_ws;
  u16*   xbT  = (u16*)(ws + oXBT);
  u16*   ek   = (u16*)(ws + oEK);
  u16*   qT   = (u16*)(ws + oQT);
  u16*   vb   = (u16*)(ws + oVB);
  u16*   Wkqv = (u16*)(ws + oWK);
  float* bias = (float*)(ws + oBIAS);
  float* ise  = (float*)(ws + oISE);
  float* ps   = (float*)(ws + oPS);
  float* ctx  = (float*)(ws + oCTX);
  u16*   Mb   = (u16*)(ws + oMB);
  float* cpart= (float*)(ws + oCPART);
  float* mpart= (float*)(ws + oMPART);

  float* attn = (float*)d_out;                    // [8][256][HW]
  float* dctx = (float*)d_out + 33554432;         // [8][32][32]
  float* dmap = (float*)d_out + 33562624;         // [8][HW]

  k_prep<<<64, 256, 0, stream>>>(Wk, Wq, Wv, bk, bq, bv, Wkqv, bias);
  k_transpose<<<dim3(256, 8), 256, 0, stream>>>(x, xbT);
  k_gemm2<0><<<1536, 256, 0, stream>>>(Wkqv, xbT, bias, ek, qT, vb, ps, nullptr);
  k_inv<<<8, 256, 0, stream>>>(ps, ise);
  k_ctx_part<<<4096, 64, 0, stream>>>(ek, vb, ise, cpart, mpart);
  k_ctx_reduce<<<64, 256, 0, stream>>>(cpart, ise, ctx, dctx);
  k_mmat<<<64, 256, 0, stream>>>(ctx, Wr, Mb);
  k_map_reduce<<<128, 256, 0, stream>>>(mpart, dmap);
  k_gemm2<1><<<512, 256, 0, stream>>>(Mb, qT, br, nullptr, nullptr, nullptr, nullptr, attn);
}

// Round 6
// 508.228 us; speedup vs baseline: 1.0003x; 1.0003x over previous
//
#include <hip/hip_runtime.h>
#include <hip/hip_bf16.h>

typedef float f32x4 __attribute__((ext_vector_type(4)));
typedef short s16x8 __attribute__((ext_vector_type(8)));
typedef short s16x4 __attribute__((ext_vector_type(4)));
typedef __bf16 bf16x8 __attribute__((ext_vector_type(8)));
typedef unsigned short u16;

#define DEVI __device__ __forceinline__

static constexpr int    HW      = 16384;
static constexpr size_t BSTRIDE = (size_t)256 * HW;

// ---- workspace byte offsets ----
static constexpr size_t oXBT   = 0;                                    // bf16 [8][HW][256]
static constexpr size_t oEK    = oXBT  + (size_t)8 * HW * 256 * 2;     // bf16 [8][256][HW] exp(keys)
static constexpr size_t oQT    = oEK   + (size_t)8 * 256 * HW * 2;     // bf16 [8][HW][256] softmaxed Q, transposed
static constexpr size_t oVB    = oQT   + (size_t)8 * HW * 256 * 2;     // bf16 [8][256][HW]
static constexpr size_t oWK    = oVB   + (size_t)8 * 256 * HW * 2;     // bf16 [768][256]
static constexpr size_t oBIAS  = oWK   + (size_t)768 * 256 * 2;        // f32 [768]
static constexpr size_t oISE   = oBIAS + 4096;                         // f32 [8][256] inv row-sum-exp
static constexpr size_t oPS    = oISE  + 8192;                         // f32 [256][8][256] rowsum partials
static constexpr size_t oCTX   = oPS   + (size_t)256 * 2048 * 4;       // f32 [64][32][32]
static constexpr size_t oMB    = oCTX  + (size_t)64 * 1024 * 4;        // bf16 [8][256][256]
static constexpr size_t oCPART = oMB   + (size_t)8 * 256 * 256 * 2;    // f32 [4096][1024]
static constexpr size_t oMPART = oCPART + (size_t)4096 * 1024 * 4;     // f32 [8][8][HW]

DEVI float bf2f(short x) {
  unsigned u = ((unsigned)(unsigned short)x) << 16;
  return __builtin_bit_cast(float, u);
}
DEVI u16 f2bf(float x) { return __builtin_bit_cast(u16, (__bf16)x); }

DEVI void gld16(const void* g, void* l) {
  __builtin_amdgcn_global_load_lds(
      (__attribute__((address_space(1))) void*)(g),
      (__attribute__((address_space(3))) void*)(l), 16, 0, 0);
}

DEVI void cfence() { asm volatile("" ::: "memory"); }

// ---------------- prep: pack Wk|Wq|Wv -> bf16 [768][256], biases -> f32 [768] ----------------
__global__ __launch_bounds__(256) void k_prep(
    const float* __restrict__ Wk, const float* __restrict__ Wq, const float* __restrict__ Wv,
    const float* __restrict__ bk, const float* __restrict__ bq, const float* __restrict__ bv,
    u16* __restrict__ Wkqv, float* __restrict__ bias)
{
  int i = blockIdx.x * 256 + threadIdx.x;
  for (int p = i; p < 768 * 256; p += 64 * 256) {
    float v = (p < 65536) ? Wk[p] : (p < 131072 ? Wq[p - 65536] : Wv[p - 131072]);
    Wkqv[p] = f2bf(v);
  }
  if (i < 768) bias[i] = (i < 256) ? bk[i] : (i < 512 ? bq[i - 256] : bv[i - 512]);
}

// ---------------- transpose x [8][256][HW] f32 -> bf16 [8][HW][256], coalesced reads ----------------
__global__ __launch_bounds__(256) void k_transpose(const float* __restrict__ x, u16* __restrict__ out)
{
  __shared__ u16 T[64 * 264];
  const int t = threadIdx.x;
  const int n = blockIdx.y;
  const int s0 = blockIdx.x * 64;
  const int cg = t >> 4;           // 0..15
  const int sl = (t & 15) * 4;     // s offset 0..60
  #pragma unroll
  for (int i = 0; i < 16; ++i) {
    const int c = i * 16 + cg;
    f32x4 v = *(const f32x4*)(x + ((size_t)n * 256 + c) * HW + s0 + sl);
    #pragma unroll
    for (int j = 0; j < 4; ++j) T[(sl + j) * 264 + c] = f2bf(v[j]);
  }
  __syncthreads();
  const int sr = t >> 2, ch = (t & 3) * 64;
  u16* dst = out + (size_t)n * BSTRIDE + (size_t)(s0 + sr) * 256 + ch;
  const u16* srcl = &T[sr * 264 + ch];
  #pragma unroll
  for (int i = 0; i < 8; ++i) *(s16x8*)(dst + i * 8) = *(const s16x8*)(srcl + i * 8);
}

// ---------------- multi-tile pipelined MFMA GEMM: 128x128 tile, BK=32, 4 s-tiles per block --------
// Counted-vmcnt double-buffer rolling across tile boundaries; T2 chunk swizzle both-sides.
// MODE 0: proj (mb 0,1 keys->exp+rowsum; 2,3 softmax-Q -> qT transposed; 4,5 values)
// MODE 1: attn = Mb * qT^T + br, f32 out
template<int MODE>
__global__ __launch_bounds__(256, 4) void k_gemm2(
    const u16* __restrict__ A, const u16* __restrict__ B, const float* __restrict__ bias,
    u16* __restrict__ o_ek, u16* __restrict__ o_qT, u16* __restrict__ o_vb,
    float* __restrict__ o_ps, float* __restrict__ o_f32)
{
  __shared__ u16 smem[16384];        // 32 KiB: A dbuf [2][128][32] | B dbuf [2][128][32]
  const int t = threadIdx.x;
  const int L = blockIdx.x;
  const int n = L & 7;               // batch == XCD
  const int idx = L >> 3;
  int mb, sq;
  if constexpr (MODE == 0) { mb = idx % 6; sq = idx / 6; }   // mb-adjacent -> B-panel L2 reuse
  else                     { mb = idx & 1; sq = idx >> 1; }
  const int m0 = mb * 128;
  const int lane = t & 63;
  const int l15 = lane & 15, l4 = (lane >> 4) & 3;
  const int wv = t >> 6;
  const int wm = (wv & 1) * 64, wn = (wv >> 1) * 64;
  const u16* Ab = A + ((MODE == 0) ? (size_t)0 : (size_t)n * 65536) + (size_t)m0 * 256;
  const u16* Bb = B + (size_t)n * BSTRIDE;
  const int ar = t >> 2;
  const int acs = (((t & 3) ^ (ar & 3)) * 8);   // pre-swizzled source chunk (involution)

  u16* Al = smem;                    // [2][4096]
  u16* Bl = smem + 8192;

  auto STAGE = [&](int it) {         // k-step (it&7) of s-tile (it>>3) into buf (it&1)
    const int buf = it & 1;
    const int k0 = (it & 7) * 32;
    const size_t srow = (size_t)((sq * 4 + (it >> 3)) * 128);
    gld16(Ab + (size_t)ar * 256 + k0 + acs,          Al + buf * 4096 + t * 8);
    gld16(Ab + (size_t)(ar + 64) * 256 + k0 + acs,   Al + buf * 4096 + 2048 + t * 8);
    gld16(Bb + (srow + ar) * 256 + k0 + acs,         Bl + buf * 4096 + t * 8);
    gld16(Bb + (srow + ar + 64) * 256 + k0 + acs,    Bl + buf * 4096 + 2048 + t * 8);
  };

  f32x4 acc[4][4] = {};
  STAGE(0);

  u16* ekb = (MODE == 0) ? o_ek + (size_t)n * BSTRIDE : nullptr;
  u16* vbb = (MODE == 0) ? o_vb + (size_t)n * BSTRIDE : nullptr;
  u16* qtb = (MODE == 0) ? o_qT + (size_t)n * BSTRIDE : nullptr;
  float* ob = (MODE == 1) ? o_f32 + (size_t)n * BSTRIDE : nullptr;

  #pragma unroll 8
  for (int it = 0; it < 32; ++it) {
    if (it < 31) {
      STAGE(it + 1);
      asm volatile("s_waitcnt vmcnt(4)" ::: "memory");   // stage(it) complete, stage(it+1) in flight
    } else {
      asm volatile("s_waitcnt vmcnt(0)" ::: "memory");
    }
    cfence(); __builtin_amdgcn_s_barrier(); cfence();

    const int buf = it & 1;
    bf16x8 af[4], bff[4];
    #pragma unroll
    for (int g = 0; g < 4; ++g) {
      const int mrow = wm + g * 16 + l15;
      const int srw  = wn + g * 16 + l15;
      af[g]  = *(const bf16x8*)&Al[buf * 4096 + mrow * 32 + ((l4 ^ (l15 & 3)) * 8)];
      bff[g] = *(const bf16x8*)&Bl[buf * 4096 + srw  * 32 + ((l4 ^ (l15 & 3)) * 8)];
    }
    __builtin_amdgcn_s_setprio(1);
    #pragma unroll
    for (int mg = 0; mg < 4; ++mg)
      #pragma unroll
      for (int ng = 0; ng < 4; ++ng)
        acc[mg][ng] = __builtin_amdgcn_mfma_f32_16x16x32_bf16(af[mg], bff[ng], acc[mg][ng], 0, 0, 0);
    __builtin_amdgcn_s_setprio(0);

    asm volatile("s_waitcnt lgkmcnt(0)" ::: "memory");   // all frag reads of buf retired
    cfence(); __builtin_amdgcn_s_barrier(); cfence();    // buf safe to overwrite next iter

    if ((it & 7) == 7) {
      // ---------------- per-tile epilogue ----------------
      const int tile = it >> 3;
      const int s0t = (sq * 4 + tile) * 128;
      if constexpr (MODE == 1) {
        #pragma unroll
        for (int mg = 0; mg < 4; ++mg)
          #pragma unroll
          for (int r = 0; r < 4; ++r) {
            const int m = m0 + wm + mg * 16 + l4 * 4 + r;
            const float bb = bias[m];
            float* op = ob + (size_t)m * HW + s0t + wn + l15;
            #pragma unroll
            for (int ng = 0; ng < 4; ++ng) op[ng * 16] = acc[mg][ng][r] + bb;
          }
      } else if (mb < 2) {
        // exp(keys) + deterministic rowsum partials
        const int stile = sq * 4 + tile;
        #pragma unroll
        for (int mg = 0; mg < 4; ++mg)
          #pragma unroll
          for (int r = 0; r < 4; ++r) {
            const int m = m0 + wm + mg * 16 + l4 * 4 + r;
            const float bb = bias[m];
            float e[4], s_ = 0.f;
            #pragma unroll
            for (int ng = 0; ng < 4; ++ng) { e[ng] = __expf(acc[mg][ng][r] + bb); s_ += e[ng]; }
            s_ += __shfl_xor(s_, 1); s_ += __shfl_xor(s_, 2);
            s_ += __shfl_xor(s_, 4); s_ += __shfl_xor(s_, 8);
            if (l15 == 0)
              o_ps[((size_t)(stile * 2 + (wn >> 6))) * 2048 + n * 256 + m] = s_;
            u16* op = ekb + (size_t)m * HW + s0t + wn + l15;
            #pragma unroll
            for (int ng = 0; ng < 4; ++ng) op[ng * 16] = f2bf(e[ng]);
          }
      } else if (mb < 4) {
        // queries: per-head (32-row) softmax over m, transposed s16x4 store to qT[s][m]
        #pragma unroll
        for (int mg = 0; mg < 4; ++mg)
          #pragma unroll
          for (int r = 0; r < 4; ++r) {
            const float bb = bias[m0 + wm + mg * 16 + l4 * 4 + r];
            #pragma unroll
            for (int ng = 0; ng < 4; ++ng) acc[mg][ng][r] += bb;
          }
        #pragma unroll
        for (int hh = 0; hh < 2; ++hh)
          #pragma unroll
          for (int ng = 0; ng < 4; ++ng) {
            float s = 0.f;
            #pragma unroll
            for (int mg = hh * 2; mg < hh * 2 + 2; ++mg)
              #pragma unroll
              for (int r = 0; r < 4; ++r) { const float e = __expf(acc[mg][ng][r]); acc[mg][ng][r] = e; s += e; }
            s += __shfl_xor(s, 16); s += __shfl_xor(s, 32);
            const float inv = 1.f / s;
            #pragma unroll
            for (int mg = hh * 2; mg < hh * 2 + 2; ++mg)
              #pragma unroll
              for (int r = 0; r < 4; ++r) acc[mg][ng][r] *= inv;
          }
        const int mcb = (m0 - 256) + wm;   // 64B-line-complete within block
        #pragma unroll
        for (int mg = 0; mg < 4; ++mg)
          #pragma unroll
          for (int ng = 0; ng < 4; ++ng) {
            s16x4 pk;
            #pragma unroll
            for (int r = 0; r < 4; ++r) pk[r] = (short)f2bf(acc[mg][ng][r]);
            *(s16x4*)(qtb + (size_t)(s0t + wn + ng * 16 + l15) * 256 + mcb + mg * 16 + l4 * 4) = pk;
          }
      } else {
        // values
        #pragma unroll
        for (int mg = 0; mg < 4; ++mg)
          #pragma unroll
          for (int r = 0; r < 4; ++r) {
            const int m = m0 + wm + mg * 16 + l4 * 4 + r;
            const float bb = bias[m];
            u16* op = vbb + (size_t)(m - 512) * HW + s0t + wn + l15;
            #pragma unroll
            for (int ng = 0; ng < 4; ++ng) op[ng * 16] = f2bf(acc[mg][ng][r] + bb);
          }
      }
      #pragma unroll
      for (int mg = 0; mg < 4; ++mg)
        #pragma unroll
        for (int ng = 0; ng < 4; ++ng) acc[mg][ng] = f32x4{0.f, 0.f, 0.f, 0.f};
    }
  }
}

// ---------------- reduce rowsum partials -> inverse ----------------
__global__ __launch_bounds__(256) void k_inv(const float* __restrict__ ps, float* __restrict__ ise)
{
  const int i = blockIdx.x * 256 + threadIdx.x;   // 2048
  float s = 0.f;
  for (int b = 0; b < 256; ++b) s += ps[(size_t)b * 2048 + i];
  ise[i] = 1.f / s;
}

// ---------------- ctx split-K partials + fused attention-map partials ----------------
__global__ __launch_bounds__(64) void k_ctx_part(
    const u16* __restrict__ ek, const u16* __restrict__ vb, const float* __restrict__ ise,
    float* __restrict__ cpart, float* __restrict__ mpart)
{
  const int blk = blockIdx.x;            // nh*64 + chunk
  const int chunk = blk & 63, nh = blk >> 6;
  const int h = nh & 7, n = nh >> 3;
  const int lane = threadIdx.x;
  const int l15 = lane & 15, l4 = lane >> 4;
  const u16* kb = ek + ((size_t)n * 256 + h * 32) * HW;
  const u16* vv = vb + ((size_t)n * 256 + h * 32) * HW;
  const float iv0 = ise[n * 256 + h * 32 + l15];
  const float iv1 = ise[n * 256 + h * 32 + 16 + l15];
  f32x4 acc[2][2] = {};
  float macc[8][8] = {};
  const int sbase = chunk * 256 + l4 * 8;
  #pragma unroll
  for (int ks = 0; ks < 8; ++ks) {
    const int sb = sbase + ks * 32;
    bf16x8 ef[2], vf[2];
    #pragma unroll
    for (int g = 0; g < 2; ++g) {
      ef[g] = *(const bf16x8*)(kb + (size_t)(g * 16 + l15) * HW + sb);
      vf[g] = *(const bf16x8*)(vv + (size_t)(g * 16 + l15) * HW + sb);
    }
    #pragma unroll
    for (int j = 0; j < 8; ++j)
      macc[ks][j] = fmaf(iv0, (float)ef[0][j], fmaf(iv1, (float)ef[1][j], macc[ks][j]));
    #pragma unroll
    for (int a = 0; a < 2; ++a)
      #pragma unroll
      for (int b = 0; b < 2; ++b)
        acc[a][b] = __builtin_amdgcn_mfma_f32_16x16x32_bf16(ef[a], vf[b], acc[a][b], 0, 0, 0);
  }
  float* op = cpart + (size_t)blk * 1024;
  #pragma unroll
  for (int a = 0; a < 2; ++a)
    #pragma unroll
    for (int b = 0; b < 2; ++b)
      #pragma unroll
      for (int r = 0; r < 4; ++r)
        op[(a * 16 + l4 * 4 + r) * 32 + b * 16 + l15] = acc[a][b][r];
  #pragma unroll
  for (int ks = 0; ks < 8; ++ks)
    #pragma unroll
    for (int j = 0; j < 8; ++j) {
      float v = macc[ks][j];
      v += __shfl_xor(v, 1); v += __shfl_xor(v, 2);
      v += __shfl_xor(v, 4); v += __shfl_xor(v, 8);
      macc[ks][j] = v;
    }
  if (l15 == 0) {
    float* mp = mpart + ((size_t)h * 8 + n) * HW + sbase;
    #pragma unroll
    for (int ks = 0; ks < 8; ++ks) {
      f32x4 a = {macc[ks][0], macc[ks][1], macc[ks][2], macc[ks][3]};
      f32x4 b = {macc[ks][4], macc[ks][5], macc[ks][6], macc[ks][7]};
      *(f32x4*)(mp + ks * 32)     = a;
      *(f32x4*)(mp + ks * 32 + 4) = b;
    }
  }
}

// ---------------- reduce ctx partials, normalize; emit context_last (h==7) ----------------
__global__ __launch_bounds__(256) void k_ctx_reduce(
    const float* __restrict__ cpart, const float* __restrict__ ise,
    float* __restrict__ ctx, float* __restrict__ dctx)
{
  const int nh = blockIdx.x, n = nh >> 3, h = nh & 7, t = threadIdx.x;
  f32x4 a = {};
  for (int c = 0; c < 64; ++c) a += *(const f32x4*)(cpart + ((size_t)nh * 64 + c) * 1024 + t * 4);
  const float inv = ise[n * 256 + h * 32 + (t >> 3)];
  a *= inv;
  *(f32x4*)(ctx + (size_t)nh * 1024 + t * 4) = a;
  if (h == 7) *(f32x4*)(dctx + (size_t)n * 1024 + t * 4) = a;
}

// ---------------- M[n][o][h*32+k] = sum_v Wr[o][h*32+v] * ctx[n][h][k][v] ----------------
__global__ __launch_bounds__(256) void k_mmat(
    const float* __restrict__ ctx, const float* __restrict__ Wr, u16* __restrict__ Mb)
{
  const int nh = blockIdx.x, n = nh >> 3, h = nh & 7, o = threadIdx.x;
  __shared__ float cl[1024];
  #pragma unroll
  for (int i = 0; i < 4; ++i) cl[o + i * 256] = ctx[(size_t)nh * 1024 + o + i * 256];
  __syncthreads();
  float wr[32];
  const float* wp = Wr + (size_t)o * 256 + h * 32;
  #pragma unroll
  for (int v = 0; v < 32; ++v) wr[v] = wp[v];
  u16* mp = Mb + ((size_t)n * 256 + o) * 256 + h * 32;
  #pragma unroll 4
  for (int k = 0; k < 32; ++k) {
    float s = 0.f;
    #pragma unroll
    for (int v = 0; v < 32; ++v) s += wr[v] * cl[k * 32 + v];
    mp[k] = f2bf(s);
  }
}

// ---------------- attention_map: sum 8 head partials, /256 ----------------
__global__ __launch_bounds__(256) void k_map_reduce(const float* __restrict__ mpart, float* __restrict__ dmap)
{
  const int i = blockIdx.x * 256 + threadIdx.x;   // 32768 threads, f32x4 each
  f32x4 a = {};
  #pragma unroll
  for (int h = 0; h < 8; ++h) a += *(const f32x4*)(mpart + (size_t)h * 131072 + (size_t)i * 4);
  a *= (1.0f / 256.0f);
  *(f32x4*)(dmap + (size_t)i * 4) = a;
}

extern "C" void kernel_launch(void* const* d_in, const int* in_sizes, int n_in,
                              void* d_out, int out_size, void* d_ws, size_t ws_size,
                              hipStream_t stream)
{
  (void)in_sizes; (void)n_in; (void)out_size; (void)ws_size;
  const float* x  = (const float*)d_in[0];
  const float* Wk = (const float*)d_in[1];
  const float* bk = (const float*)d_in[2];
  const float* Wq = (const float*)d_in[3];
  const float* bq = (const float*)d_in[4];
  const float* Wv = (const float*)d_in[5];
  const float* bv = (const float*)d_in[6];
  const float* Wr = (const float*)d_in[7];
  const float* br = (const float*)d_in[8];

  char* ws = (char*)d_ws;
  u16*   xbT  = (u16*)(ws + oXBT);
  u16*   ek   = (u16*)(ws + oEK);
  u16*   qT   = (u16*)(ws + oQT);
  u16*   vb   = (u16*)(ws + oVB);
  u16*   Wkqv = (u16*)(ws + oWK);
  float* bias = (float*)(ws + oBIAS);
  float* ise  = (float*)(ws + oISE);
  float* ps   = (float*)(ws + oPS);
  float* ctx  = (float*)(ws + oCTX);
  u16*   Mb   = (u16*)(ws + oMB);
  float* cpart= (float*)(ws + oCPART);
  float* mpart= (float*)(ws + oMPART);

  float* attn = (float*)d_out;                    // [8][256][HW]
  float* dctx = (float*)d_out + 33554432;         // [8][32][32]
  float* dmap = (float*)d_out + 33562624;         // [8][HW]

  k_prep<<<64, 256, 0, stream>>>(Wk, Wq, Wv, bk, bq, bv, Wkqv, bias);
  k_transpose<<<dim3(256, 8), 256, 0, stream>>>(x, xbT);
  k_gemm2<0><<<1536, 256, 0, stream>>>(Wkqv, xbT, bias, ek, qT, vb, ps, nullptr);
  k_inv<<<8, 256, 0, stream>>>(ps, ise);
  k_ctx_part<<<4096, 64, 0, stream>>>(ek, vb, ise, cpart, mpart);
  k_ctx_reduce<<<64, 256, 0, stream>>>(cpart, ise, ctx, dctx);
  k_mmat<<<64, 256, 0, stream>>>(ctx, Wr, Mb);
  k_map_reduce<<<128, 256, 0, stream>>>(mpart, dmap);
  k_gemm2<1><<<512, 256, 0, stream>>>(Mb, qT, br, nullptr, nullptr, nullptr, nullptr, attn);
}

// Round 7
// 287.122 us; speedup vs baseline: 1.7706x; 1.7701x over previous
//
#include <hip/hip_runtime.h>
#include <hip/hip_bf16.h>

typedef float f32x4 __attribute__((ext_vector_type(4)));
typedef short s16x8 __attribute__((ext_vector_type(8)));
typedef short s16x4 __attribute__((ext_vector_type(4)));
typedef __bf16 bf16x8 __attribute__((ext_vector_type(8)));
typedef unsigned short u16;

#define DEVI __device__ __forceinline__

static constexpr int    HW      = 16384;
static constexpr size_t BSTRIDE = (size_t)256 * HW;

// ---- workspace byte offsets ----
static constexpr size_t oXBT   = 0;                                    // bf16 [8][HW][256]
static constexpr size_t oEK    = oXBT  + (size_t)8 * HW * 256 * 2;     // bf16 [8][256][HW] exp(keys)
static constexpr size_t oQT    = oEK   + (size_t)8 * 256 * HW * 2;     // bf16 [8][HW][256] softmaxed Q, transposed
static constexpr size_t oVB    = oQT   + (size_t)8 * HW * 256 * 2;     // bf16 [8][256][HW]
static constexpr size_t oWK    = oVB   + (size_t)8 * 256 * HW * 2;     // bf16 [768][256]
static constexpr size_t oBIAS  = oWK   + (size_t)768 * 256 * 2;        // f32 [768]
static constexpr size_t oISE   = oBIAS + 4096;                         // f32 [8][256] inv row-sum-exp
static constexpr size_t oPS    = oISE  + 8192;                         // f32 [256][8][256] rowsum partials
static constexpr size_t oCTX   = oPS   + (size_t)256 * 2048 * 4;       // f32 [64][32][32]
static constexpr size_t oMB    = oCTX  + (size_t)64 * 1024 * 4;        // bf16 [8][256][256]
static constexpr size_t oCPART = oMB   + (size_t)8 * 256 * 256 * 2;    // f32 [4096][1024]
static constexpr size_t oMPART = oCPART + (size_t)4096 * 1024 * 4;     // f32 [8][8][HW]

DEVI float bf2f(short x) {
  unsigned u = ((unsigned)(unsigned short)x) << 16;
  return __builtin_bit_cast(float, u);
}
DEVI u16 f2bf(float x) { return __builtin_bit_cast(u16, (__bf16)x); }

DEVI void gld16(const void* g, void* l) {
  __builtin_amdgcn_global_load_lds(
      (__attribute__((address_space(1))) void*)(g),
      (__attribute__((address_space(3))) void*)(l), 16, 0, 0);
}

// ---------------- prep: pack Wk|Wq|Wv -> bf16 [768][256], biases -> f32 [768] ----------------
__global__ __launch_bounds__(256) void k_prep(
    const float* __restrict__ Wk, const float* __restrict__ Wq, const float* __restrict__ Wv,
    const float* __restrict__ bk, const float* __restrict__ bq, const float* __restrict__ bv,
    u16* __restrict__ Wkqv, float* __restrict__ bias)
{
  int i = blockIdx.x * 256 + threadIdx.x;
  for (int p = i; p < 768 * 256; p += 64 * 256) {
    float v = (p < 65536) ? Wk[p] : (p < 131072 ? Wq[p - 65536] : Wv[p - 131072]);
    Wkqv[p] = f2bf(v);
  }
  if (i < 768) bias[i] = (i < 256) ? bk[i] : (i < 512 ? bq[i - 256] : bv[i - 512]);
}

// ---------------- transpose x [8][256][HW] f32 -> bf16 [8][HW][256] (round-2 proven) ----------------
__global__ __launch_bounds__(256) void k_transpose(const float* __restrict__ in_, u16* __restrict__ out)
{
  __shared__ u16 lds[64 * 256];
  const int t = threadIdx.x;
  const int n = blockIdx.y;
  const int s0 = blockIdx.x * 64;
  const float* src = in_ + ((size_t)n * 256 + t) * HW + s0;
  #pragma unroll
  for (int i = 0; i < 16; ++i) {
    f32x4 v = *(const f32x4*)(src + i * 4);
    #pragma unroll
    for (int j = 0; j < 4; ++j) lds[(i * 4 + j) * 256 + t] = f2bf(v[j]);
  }
  __syncthreads();
  s16x8* gp = (s16x8*)(out + (size_t)n * BSTRIDE + (size_t)s0 * 256);
  const s16x8* lp = (const s16x8*)lds;
  #pragma unroll
  for (int i = 0; i < 8; ++i) gp[t + i * 256] = lp[t + i * 256];
}

// ======== shared k-loop core: 128x128 tile, BK=64, depth-1 counted-vmcnt, swizzled LDS ========
// smem layout (u16): A dbuf [2][8192] | B dbuf [2][8192]  (64 KiB total)
// acc[mg][ng][r]: m = m0 + wm + mg*16 + l4*4 + r ; s = s0 + wn + ng*16 + l15

#define GEMM_CORE(Ab, Bb)                                                                   \
  u16* Al = smem;                                                                           \
  u16* Bl = smem + 16384;                                                                   \
  auto STAGE = [&](int buf, int kt) {                                                       \
    const int k0 = kt * 64;                                                                 \
    _Pragma("unroll")                                                                       \
    for (int i = 0; i < 4; ++i) {                                                           \
      const int r_ = i * 32 + (t >> 3);                                                     \
      const int cs = (((t & 7) ^ (r_ & 7)) * 8);                                            \
      gld16((Ab) + (size_t)r_ * 256 + k0 + cs, Al + buf * 8192 + i * 2048 + t * 8);         \
      gld16((Bb) + (size_t)r_ * 256 + k0 + cs, Bl + buf * 8192 + i * 2048 + t * 8);         \
    }                                                                                       \
  };                                                                                        \
  f32x4 acc[4][4] = {};                                                                     \
  STAGE(0, 0); STAGE(1, 1);                                                                 \
  _Pragma("unroll")                                                                         \
  for (int kt = 0; kt < 4; ++kt) {                                                          \
    if (kt < 3) asm volatile("s_waitcnt vmcnt(8)" ::: "memory");                            \
    else        asm volatile("s_waitcnt vmcnt(0)" ::: "memory");                            \
    __builtin_amdgcn_s_barrier();                                                           \
    const int buf = kt & 1;                                                                 \
    _Pragma("unroll")                                                                       \
    for (int ks = 0; ks < 2; ++ks) {                                                        \
      bf16x8 af[4], bff[4];                                                                 \
      _Pragma("unroll")                                                                     \
      for (int g = 0; g < 4; ++g) {                                                         \
        const int mrow = wm + g * 16 + l15;                                                 \
        const int srow = wn + g * 16 + l15;                                                 \
        af[g]  = *(const bf16x8*)&Al[buf * 8192 + mrow * 64 + (((ks * 4 + l4) ^ (mrow & 7)) * 8)]; \
        bff[g] = *(const bf16x8*)&Bl[buf * 8192 + srow * 64 + (((ks * 4 + l4) ^ (srow & 7)) * 8)]; \
      }                                                                                     \
      __builtin_amdgcn_s_setprio(1);                                                        \
      _Pragma("unroll")                                                                     \
      for (int mg = 0; mg < 4; ++mg)                                                        \
        _Pragma("unroll")                                                                   \
        for (int ng = 0; ng < 4; ++ng)                                                      \
          acc[mg][ng] = __builtin_amdgcn_mfma_f32_16x16x32_bf16(af[mg], bff[ng], acc[mg][ng], 0, 0, 0); \
      __builtin_amdgcn_s_setprio(0);                                                        \
    }                                                                                       \
    asm volatile("s_waitcnt lgkmcnt(0)" ::: "memory");                                      \
    __builtin_amdgcn_s_barrier();                                                           \
    if (kt < 2) STAGE(buf, kt + 2);                                                         \
  }

// ---------------- fused projection GEMM: [768]x[256]x[HW] per batch ----------------
__global__ __launch_bounds__(256, 2) void k_proj(
    const u16* __restrict__ W, const u16* __restrict__ xbT, const float* __restrict__ bias,
    u16* __restrict__ ek, u16* __restrict__ qT, u16* __restrict__ vb, float* __restrict__ ps)
{
  __shared__ u16 smem[32768];          // 64 KiB dbuf; epilogue overlay reuses first 34 KiB
  const int t = threadIdx.x;
  const int L = blockIdx.x;
  const int n  = L & 7;                // one batch per XCD
  const int idx = L >> 3;
  const int mb = idx % 6;              // m-blocks adjacent -> B-panel L2 reuse
  const int sb = idx / 6;
  const int m0 = mb * 128, s0 = sb * 128;
  const int lane = t & 63;
  const int l15 = lane & 15, l4 = (lane >> 4) & 3;
  const int wv = t >> 6;
  const int wm = (wv & 1) * 64, wn = (wv >> 1) * 64;
  const u16* Ab = W + (size_t)m0 * 256;
  const u16* Bb = xbT + (size_t)n * BSTRIDE + (size_t)s0 * 256;

  GEMM_CORE(Ab, Bb)

  #pragma unroll
  for (int mg = 0; mg < 4; ++mg)
    #pragma unroll
    for (int r = 0; r < 4; ++r) {
      const float bb = bias[m0 + wm + mg * 16 + l4 * 4 + r];
      #pragma unroll
      for (int ng = 0; ng < 4; ++ng) acc[mg][ng][r] += bb;
    }

  const int rowBase = (mb & 1) * 128;

  if (mb < 2) {
    // keys: exp in f32, deterministic per-(block,wave-half) row-sum partials, bf16 store
    #pragma unroll
    for (int mg = 0; mg < 4; ++mg)
      #pragma unroll
      for (int r = 0; r < 4; ++r) {
        float s_ = 0.f;
        #pragma unroll
        for (int ng = 0; ng < 4; ++ng) {
          const float e = __expf(acc[mg][ng][r]);
          acc[mg][ng][r] = e; s_ += e;
        }
        s_ += __shfl_xor(s_, 1); s_ += __shfl_xor(s_, 2);
        s_ += __shfl_xor(s_, 4); s_ += __shfl_xor(s_, 8);
        if (l15 == 0) {
          const int row = rowBase + wm + mg * 16 + l4 * 4 + r;
          ps[((size_t)(sb * 2 + (wn >> 6))) * 2048 + n * 256 + row] = s_;
        }
      }
    u16* O = ek + (size_t)n * BSTRIDE;
    #pragma unroll
    for (int mg = 0; mg < 4; ++mg)
      #pragma unroll
      for (int r = 0; r < 4; ++r) {
        const size_t row = rowBase + wm + mg * 16 + l4 * 4 + r;
        u16* op = O + row * HW + s0 + wn + l15;
        #pragma unroll
        for (int ng = 0; ng < 4; ++ng) op[ng * 16] = f2bf(acc[mg][ng][r]);
      }
  } else if (mb < 4) {
    // queries: softmax over each 32-row head, then transposed store via padded LDS tile
    #pragma unroll
    for (int hh = 0; hh < 2; ++hh)
      #pragma unroll
      for (int ng = 0; ng < 4; ++ng) {
        float s = 0.f;
        #pragma unroll
        for (int mg = hh * 2; mg < hh * 2 + 2; ++mg)
          #pragma unroll
          for (int r = 0; r < 4; ++r) { const float e = __expf(acc[mg][ng][r]); acc[mg][ng][r] = e; s += e; }
        s += __shfl_xor(s, 16);
        s += __shfl_xor(s, 32);
        const float inv = 1.f / s;
        #pragma unroll
        for (int mg = hh * 2; mg < hh * 2 + 2; ++mg)
          #pragma unroll
          for (int r = 0; r < 4; ++r) acc[mg][ng][r] *= inv;
      }
    // acc at (m = wm+mg*16+l4*4+r, s = wn+ng*16+l15); write [s][m] tile via padded LDS
    __syncthreads();
    #pragma unroll
    for (int mg = 0; mg < 4; ++mg)
      #pragma unroll
      for (int ng = 0; ng < 4; ++ng)
        #pragma unroll
        for (int r = 0; r < 4; ++r) {
          const int srow = wn + ng * 16 + l15;
          const int mcol = wm + mg * 16 + l4 * 4 + r;
          smem[srow * 136 + mcol] = f2bf(acc[mg][ng][r]);
        }
    __syncthreads();
    u16* O = qT + (size_t)n * BSTRIDE + (size_t)s0 * 256 + rowBase;
    #pragma unroll
    for (int it = 0; it < 8; ++it) {
      const int row = it * 16 + (t >> 4);
      *(s16x8*)(O + (size_t)row * 256 + (t & 15) * 8) = *(const s16x8*)&smem[row * 136 + (t & 15) * 8];
    }
  } else {
    // values: plain bf16 store
    u16* O = vb + (size_t)n * BSTRIDE;
    #pragma unroll
    for (int mg = 0; mg < 4; ++mg)
      #pragma unroll
      for (int r = 0; r < 4; ++r) {
        const size_t row = rowBase + wm + mg * 16 + l4 * 4 + r;
        u16* op = O + row * HW + s0 + wn + l15;
        #pragma unroll
        for (int ng = 0; ng < 4; ++ng) op[ng * 16] = f2bf(acc[mg][ng][r]);
      }
  }
}

// ---------------- final GEMM: attn[o][s] = sum_m M[o][m] * Q[s][m] + br, f32 out ----------------
__global__ __launch_bounds__(256, 2) void k_attn(
    const u16* __restrict__ Mb, const u16* __restrict__ qT, const float* __restrict__ br,
    float* __restrict__ Out)
{
  __shared__ u16 smem[32768];
  const int t = threadIdx.x;
  const int L = blockIdx.x;
  const int n = L & 7;
  const int idx = L >> 3;
  const int m0 = (idx & 1) * 128;
  const int s0 = (idx >> 1) * 128;
  const int lane = t & 63;
  const int l15 = lane & 15, l4 = (lane >> 4) & 3;
  const int wv = t >> 6;
  const int wm = (wv & 1) * 64, wn = (wv >> 1) * 64;
  const u16* Ab = Mb + (size_t)n * 65536 + (size_t)m0 * 256;
  const u16* Bb = qT + (size_t)n * BSTRIDE + (size_t)s0 * 256;

  GEMM_CORE(Ab, Bb)

  float* O = Out + (size_t)n * BSTRIDE;
  #pragma unroll
  for (int mg = 0; mg < 4; ++mg)
    #pragma unroll
    for (int r = 0; r < 4; ++r) {
      const size_t row = m0 + wm + mg * 16 + l4 * 4 + r;
      const float bb = br[row];
      float* op = O + row * HW + s0 + wn + l15;
      #pragma unroll
      for (int ng = 0; ng < 4; ++ng) op[ng * 16] = acc[mg][ng][r] + bb;
    }
}

// ---------------- reduce rowsum partials -> inverse ----------------
__global__ __launch_bounds__(256) void k_inv(const float* __restrict__ ps, float* __restrict__ ise)
{
  const int i = blockIdx.x * 256 + threadIdx.x;   // 2048
  float s = 0.f;
  for (int b = 0; b < 256; ++b) s += ps[(size_t)b * 2048 + i];
  ise[i] = 1.f / s;
}

// ---------------- ctx split-K partials + fused attention-map partials ----------------
__global__ __launch_bounds__(64) void k_ctx_part(
    const u16* __restrict__ ek, const u16* __restrict__ vb, const float* __restrict__ ise,
    float* __restrict__ cpart, float* __restrict__ mpart)
{
  const int blk = blockIdx.x;            // nh*64 + chunk
  const int chunk = blk & 63, nh = blk >> 6;
  const int h = nh & 7, n = nh >> 3;
  const int lane = threadIdx.x;
  const int l15 = lane & 15, l4 = lane >> 4;
  const u16* kb = ek + ((size_t)n * 256 + h * 32) * HW;
  const u16* vv = vb + ((size_t)n * 256 + h * 32) * HW;
  const float iv0 = ise[n * 256 + h * 32 + l15];
  const float iv1 = ise[n * 256 + h * 32 + 16 + l15];
  f32x4 acc[2][2] = {};
  float macc[8][8] = {};
  const int sbase = chunk * 256 + l4 * 8;
  #pragma unroll
  for (int ks = 0; ks < 8; ++ks) {
    const int sb = sbase + ks * 32;
    bf16x8 ef[2], vf[2];
    #pragma unroll
    for (int g = 0; g < 2; ++g) {
      ef[g] = *(const bf16x8*)(kb + (size_t)(g * 16 + l15) * HW + sb);
      vf[g] = *(const bf16x8*)(vv + (size_t)(g * 16 + l15) * HW + sb);
    }
    #pragma unroll
    for (int j = 0; j < 8; ++j)
      macc[ks][j] = fmaf(iv0, (float)ef[0][j], fmaf(iv1, (float)ef[1][j], macc[ks][j]));
    #pragma unroll
    for (int a = 0; a < 2; ++a)
      #pragma unroll
      for (int b = 0; b < 2; ++b)
        acc[a][b] = __builtin_amdgcn_mfma_f32_16x16x32_bf16(ef[a], vf[b], acc[a][b], 0, 0, 0);
  }
  float* op = cpart + (size_t)blk * 1024;
  #pragma unroll
  for (int a = 0; a < 2; ++a)
    #pragma unroll
    for (int b = 0; b < 2; ++b)
      #pragma unroll
      for (int r = 0; r < 4; ++r)
        op[(a * 16 + l4 * 4 + r) * 32 + b * 16 + l15] = acc[a][b][r];
  #pragma unroll
  for (int ks = 0; ks < 8; ++ks)
    #pragma unroll
    for (int j = 0; j < 8; ++j) {
      float v = macc[ks][j];
      v += __shfl_xor(v, 1); v += __shfl_xor(v, 2);
      v += __shfl_xor(v, 4); v += __shfl_xor(v, 8);
      macc[ks][j] = v;
    }
  if (l15 == 0) {
    float* mp = mpart + ((size_t)h * 8 + n) * HW + sbase;
    #pragma unroll
    for (int ks = 0; ks < 8; ++ks) {
      f32x4 a = {macc[ks][0], macc[ks][1], macc[ks][2], macc[ks][3]};
      f32x4 b = {macc[ks][4], macc[ks][5], macc[ks][6], macc[ks][7]};
      *(f32x4*)(mp + ks * 32)     = a;
      *(f32x4*)(mp + ks * 32 + 4) = b;
    }
  }
}

// ---------------- reduce ctx partials, normalize; emit context_last (h==7) ----------------
__global__ __launch_bounds__(256) void k_ctx_reduce(
    const float* __restrict__ cpart, const float* __restrict__ ise,
    float* __restrict__ ctx, float* __restrict__ dctx)
{
  const int nh = blockIdx.x, n = nh >> 3, h = nh & 7, t = threadIdx.x;
  f32x4 a = {};
  for (int c = 0; c < 64; ++c) a += *(const f32x4*)(cpart + ((size_t)nh * 64 + c) * 1024 + t * 4);
  const float inv = ise[n * 256 + h * 32 + (t >> 3)];
  a *= inv;
  *(f32x4*)(ctx + (size_t)nh * 1024 + t * 4) = a;
  if (h == 7) *(f32x4*)(dctx + (size_t)n * 1024 + t * 4) = a;
}

// ---------------- M[n][o][h*32+k] = sum_v Wr[o][h*32+v] * ctx[n][h][k][v] ----------------
__global__ __launch_bounds__(256) void k_mmat(
    const float* __restrict__ ctx, const float* __restrict__ Wr, u16* __restrict__ Mb)
{
  const int nh = blockIdx.x, n = nh >> 3, h = nh & 7, o = threadIdx.x;
  __shared__ float cl[1024];
  #pragma unroll
  for (int i = 0; i < 4; ++i) cl[o + i * 256] = ctx[(size_t)nh * 1024 + o + i * 256];
  __syncthreads();
  float wr[32];
  const float* wp = Wr + (size_t)o * 256 + h * 32;
  #pragma unroll
  for (int v = 0; v < 32; ++v) wr[v] = wp[v];
  u16* mp = Mb + ((size_t)n * 256 + o) * 256 + h * 32;
  #pragma unroll 4
  for (int k = 0; k < 32; ++k) {
    float s = 0.f;
    #pragma unroll
    for (int v = 0; v < 32; ++v) s += wr[v] * cl[k * 32 + v];
    mp[k] = f2bf(s);
  }
}

// ---------------- attention_map: sum 8 head partials, /256 ----------------
__global__ __launch_bounds__(256) void k_map_reduce(const float* __restrict__ mpart, float* __restrict__ dmap)
{
  const int i = blockIdx.x * 256 + threadIdx.x;   // 32768 threads, f32x4 each
  f32x4 a = {};
  #pragma unroll
  for (int h = 0; h < 8; ++h) a += *(const f32x4*)(mpart + (size_t)h * 131072 + (size_t)i * 4);
  a *= (1.0f / 256.0f);
  *(f32x4*)(dmap + (size_t)i * 4) = a;
}

extern "C" void kernel_launch(void* const* d_in, const int* in_sizes, int n_in,
                              void* d_out, int out_size, void* d_ws, size_t ws_size,
                              hipStream_t stream)
{
  (void)in_sizes; (void)n_in; (void)out_size; (void)ws_size;
  const float* x  = (const float*)d_in[0];
  const float* Wk = (const float*)d_in[1];
  const float* bk = (const float*)d_in[2];
  const float* Wq = (const float*)d_in[3];
  const float* bq = (const float*)d_in[4];
  const float* Wv = (const float*)d_in[5];
  const float* bv = (const float*)d_in[6];
  const float* Wr = (const float*)d_in[7];
  const float* br = (const float*)d_in[8];

  char* ws = (char*)d_ws;
  u16*   xbT  = (u16*)(ws + oXBT);
  u16*   ek   = (u16*)(ws + oEK);
  u16*   qT   = (u16*)(ws + oQT);
  u16*   vb   = (u16*)(ws + oVB);
  u16*   Wkqv = (u16*)(ws + oWK);
  float* bias = (float*)(ws + oBIAS);
  float* ise  = (float*)(ws + oISE);
  float* ps   = (float*)(ws + oPS);
  float* ctx  = (float*)(ws + oCTX);
  u16*   Mb   = (u16*)(ws + oMB);
  float* cpart= (float*)(ws + oCPART);
  float* mpart= (float*)(ws + oMPART);

  float* attn = (float*)d_out;                    // [8][256][HW]
  float* dctx = (float*)d_out + 33554432;         // [8][32][32]
  float* dmap = (float*)d_out + 33562624;         // [8][HW]

  k_prep<<<64, 256, 0, stream>>>(Wk, Wq, Wv, bk, bq, bv, Wkqv, bias);
  k_transpose<<<dim3(256, 8), 256, 0, stream>>>(x, xbT);
  k_proj<<<6144, 256, 0, stream>>>(Wkqv, xbT, bias, ek, qT, vb, ps);
  k_inv<<<8, 256, 0, stream>>>(ps, ise);
  k_ctx_part<<<4096, 64, 0, stream>>>(ek, vb, ise, cpart, mpart);
  k_ctx_reduce<<<64, 256, 0, stream>>>(cpart, ise, ctx, dctx);
  k_mmat<<<64, 256, 0, stream>>>(ctx, Wr, Mb);
  k_map_reduce<<<128, 256, 0, stream>>>(mpart, dmap);
  k_attn<<<2048, 256, 0, stream>>>(Mb, qT, br, attn);
}